// Round 19
// baseline (165.936 us; speedup 1.0000x reference)
//
#include <hip/hip_runtime.h>
#include <math.h>

#define HH 56
#define WW 56
#define CC 256
#define TT 8
#define HW 3136

// ---------------- K0: zero workspace (replaces slow runtime fill) ---------
__global__ void k0_zero(float4* __restrict__ p, int n4) {
    int i = blockIdx.x * 256 + threadIdx.x;
    if (i < n4) p[i] = make_float4(0.f, 0.f, 0.f, 0.f);
}

// ---------------- K1: attn conv2d, channel-vectorized LDS (r11 exact) -----
// 4-ch windows (144 weights = SGPR-budget sweet spot; 8-ch demotes weights
// to VALU loads, 3x regression - r13/r14). csplit 8 -> 3584 blocks.
__global__ __launch_bounds__(256)
void k1_attn(const float* __restrict__ x, const float* __restrict__ aw,
             float* __restrict__ attn_raw) {
    const int blk = blockIdx.x;
    const int cs  = blk & 7;
    const int ht  = (blk >> 3) % 14;
    const int bt  = blk / 112;
    const int h0  = ht * 4;
    __shared__ float tile[2][348 * 4];      // 11136 B
    const int tid = threadIdx.x;
    const float* xb = x + ((size_t)bt * CC + cs * 32) * HW;

    int  pgoff[2];
    bool pvld[2];
    #pragma unroll
    for (int k = 0; k < 2; ++k) {
        int p = tid + k * 256;
        bool in = p < 348;
        int r   = p / 58;
        int col = p - r * 58;
        int gh = h0 + r - 1, gw = col - 1;
        bool v = in && (unsigned)gh < HH && (unsigned)gw < WW;
        pvld[k]  = v;
        pgoff[k] = gh * WW + gw;
        if (in && !v) {
            float4 z = make_float4(0.f, 0.f, 0.f, 0.f);
            *(float4*)&tile[0][p * 4] = z;
            *(float4*)&tile[1][p * 4] = z;
        }
    }

    #pragma unroll
    for (int k = 0; k < 2; ++k)
        if (pvld[k]) {
            float v0 = xb[(size_t)0 * HW + pgoff[k]];
            float v1 = xb[(size_t)1 * HW + pgoff[k]];
            float v2 = xb[(size_t)2 * HW + pgoff[k]];
            float v3 = xb[(size_t)3 * HW + pgoff[k]];
            *(float4*)&tile[0][(tid + k * 256) * 4] = make_float4(v0, v1, v2, v3);
        }
    __syncthreads();

    const int wc = tid % WW;
    const int hr = tid / WW;
    const bool active = tid < 4 * WW;
    float acc[4] = {0.f, 0.f, 0.f, 0.f};

    for (int it = 0; it < 8; ++it) {
        const int c0 = cs * 32 + it * 4;
        float xn[2][4];
        if (it < 7) {
            #pragma unroll
            for (int k = 0; k < 2; ++k)
                if (pvld[k]) {
                    #pragma unroll
                    for (int j = 0; j < 4; ++j)
                        xn[k][j] = xb[(size_t)(it * 4 + 4 + j) * HW + pgoff[k]];
                }
        }
        if (active) {
            const float* buf = &tile[it & 1][0];
            const float* w0 = aw + ((size_t)0 * CC + c0) * 9;
            const float* w1 = aw + ((size_t)1 * CC + c0) * 9;
            const float* w2 = aw + ((size_t)2 * CC + c0) * 9;
            const float* w3 = aw + ((size_t)3 * CC + c0) * 9;
            #pragma unroll
            for (int ki = 0; ki < 3; ++ki) {
                #pragma unroll
                for (int kj = 0; kj < 3; ++kj) {
                    const int tap = ki * 3 + kj;
                    const int pos = (hr + ki) * 58 + wc + kj;
                    const float4 v = *(const float4*)(buf + pos * 4);
                    acc[0] = fmaf(w0[tap],      v.x, acc[0]);
                    acc[0] = fmaf(w0[9  + tap], v.y, acc[0]);
                    acc[0] = fmaf(w0[18 + tap], v.z, acc[0]);
                    acc[0] = fmaf(w0[27 + tap], v.w, acc[0]);
                    acc[1] = fmaf(w1[tap],      v.x, acc[1]);
                    acc[1] = fmaf(w1[9  + tap], v.y, acc[1]);
                    acc[1] = fmaf(w1[18 + tap], v.z, acc[1]);
                    acc[1] = fmaf(w1[27 + tap], v.w, acc[1]);
                    acc[2] = fmaf(w2[tap],      v.x, acc[2]);
                    acc[2] = fmaf(w2[9  + tap], v.y, acc[2]);
                    acc[2] = fmaf(w2[18 + tap], v.z, acc[2]);
                    acc[2] = fmaf(w2[27 + tap], v.w, acc[2]);
                    acc[3] = fmaf(w3[tap],      v.x, acc[3]);
                    acc[3] = fmaf(w3[9  + tap], v.y, acc[3]);
                    acc[3] = fmaf(w3[18 + tap], v.z, acc[3]);
                    acc[3] = fmaf(w3[27 + tap], v.w, acc[3]);
                }
            }
        }
        if (it < 7) {
            float* bufn = &tile[(it + 1) & 1][0];
            #pragma unroll
            for (int k = 0; k < 2; ++k)
                if (pvld[k])
                    *(float4*)&bufn[(tid + k * 256) * 4] =
                        make_float4(xn[k][0], xn[k][1], xn[k][2], xn[k][3]);
        }
        __syncthreads();
    }

    if (active) {
        const int base = (h0 + hr) * WW + wc;
        #pragma unroll
        for (int h = 0; h < 4; ++h)
            atomicAdd(&attn_raw[((size_t)bt * 4 + h) * HW + base], acc[h]);
    }
}

// ---------------- K2: BN partial sums + fused attn activation -------------
__global__ __launch_bounds__(256)
void k2_stats(const float* __restrict__ x, const float* __restrict__ attn_raw,
              const float* __restrict__ ab, float* __restrict__ attn,
              float* __restrict__ bn_sum, float* __restrict__ bn_sumsq) {
    const int c  = blockIdx.x & 255;
    const int bt = blockIdx.x >> 8;
    const int head = c >> 6;
    const float bias = ab[head];
    const bool wr = (c & 63) == 0;
    const float4* xp = (const float4*)(x + ((size_t)bt * CC + c) * HW);
    const float4* rp = (const float4*)(attn_raw + ((size_t)bt * 4 + head) * HW);
    float4* ap = (float4*)(attn + ((size_t)bt * 4 + head) * HW);
    float s = 0.f, s2 = 0.f;
    for (int i = threadIdx.x; i < HW / 4; i += 256) {
        float4 rv = rp[i];
        float4 av;
        av.x = 1.f / (1.f + expf(-fmaxf(rv.x + bias, 0.f)));
        av.y = 1.f / (1.f + expf(-fmaxf(rv.y + bias, 0.f)));
        av.z = 1.f / (1.f + expf(-fmaxf(rv.z + bias, 0.f)));
        av.w = 1.f / (1.f + expf(-fmaxf(rv.w + bias, 0.f)));
        if (wr) ap[i] = av;
        float4 xv = xp[i];
        float v0 = xv.x * av.x, v1 = xv.y * av.y, v2 = xv.z * av.z, v3 = xv.w * av.w;
        s  += v0 + v1 + v2 + v3;
        s2 += v0 * v0 + v1 * v1 + v2 * v2 + v3 * v3;
    }
    #pragma unroll
    for (int off = 32; off > 0; off >>= 1) {
        s  += __shfl_down(s, off);
        s2 += __shfl_down(s2, off);
    }
    __shared__ float red[8];
    const int wave = threadIdx.x >> 6;
    if ((threadIdx.x & 63) == 0) { red[wave * 2] = s; red[wave * 2 + 1] = s2; }
    __syncthreads();
    if (threadIdx.x == 0) {
        atomicAdd(&bn_sum[c],   red[0] + red[2] + red[4] + red[6]);
        atomicAdd(&bn_sumsq[c], red[1] + red[3] + red[5] + red[7]);
    }
}

// ---------------- K3: finalize BN -> per-channel scale/shift --------------
__global__ void k3_final(const float* __restrict__ bn_sum, const float* __restrict__ bn_sumsq,
                         const float* __restrict__ gamma, const float* __restrict__ beta,
                         float* __restrict__ scale, float* __restrict__ shift) {
    int c = threadIdx.x;
    const float invN = 1.f / 100352.f;            // B*T*H*W
    float mean = bn_sum[c] * invN;
    float var  = bn_sumsq[c] * invN - mean * mean;
    float sc   = gamma[c] * rsqrtf(var + 1e-5f);
    scale[c] = sc;
    shift[c] = fmaf(-mean, sc, beta[c]);
}

// ---------------- K4: grouped dilated conv3d, t-vectorized single-buffer --
// r16 exact (best measured). NO launch_bounds min-waves: forcing 7 waves/EU
// (r17) made the compiler spill acc[] to scratch (VGPR 80->36, +320MB
// scratch traffic, 52->131us). 80 VGPR / 6 blocks/CU is the right point.
__global__ __launch_bounds__(256)
void k4_gate(const float* __restrict__ x, const float* __restrict__ attn,
             const float* __restrict__ scale, const float* __restrict__ shift,
             const float* __restrict__ gw0, const float* __restrict__ gw1,
             float* __restrict__ gate_raw) {
    const int blk   = blockIdx.x;
    const int chunk = blk & 31;             // 32 chunks x 8 channels
    const int ht    = (blk >> 5) % 14;
    const int b     = blk / (32 * 14);
    const int h0    = ht * 4;
    const int g     = chunk >> 4;           // group: ch 0..127 -> 0, else 1
    const int head  = chunk >> 3;           // 8-ch chunk sits inside one head
    __shared__ float tile[348 * 12];        // 16704 B (single buffer)
    const int tid = threadIdx.x;

    int   pgoff[2];
    bool  pvld[2];
    float pav[2][8];
    #pragma unroll
    for (int k = 0; k < 2; ++k) {
        int p = tid + k * 256;
        bool in = p < 348;
        int r   = p / 58;
        int col = p - r * 58;
        int gh = h0 + r - 1, gw = col - 1;
        bool v = in && (unsigned)gh < HH && (unsigned)gw < WW;
        pvld[k]  = v;
        pgoff[k] = gh * WW + gw;
        #pragma unroll
        for (int t = 0; t < 8; ++t)
            pav[k][t] = v ? attn[((size_t)(b * 8 + t) * 4 + head) * HW + pgoff[k]] : 0.f;
        if (in && !v) {                      // zero halo once
            float4 z = make_float4(0.f, 0.f, 0.f, 0.f);
            *(float4*)&tile[p * 12]     = z;
            *(float4*)&tile[p * 12 + 4] = z;
        }
    }

    // stage channel 0
    {
        const int c0 = chunk * 8;
        const float sc = scale[c0], sh = shift[c0];
        #pragma unroll
        for (int k = 0; k < 2; ++k)
            if (pvld[k]) {
                float v[8];
                #pragma unroll
                for (int t = 0; t < 8; ++t) {
                    float xv = x[((size_t)((b * 8 + t) * CC + c0)) * HW + pgoff[k]];
                    v[t] = fmaxf(fmaf(xv * pav[k][t], sc, sh), 0.f);
                }
                int p = tid + k * 256;
                *(float4*)&tile[p * 12]     = make_float4(v[0], v[1], v[2], v[3]);
                *(float4*)&tile[p * 12 + 4] = make_float4(v[4], v[5], v[6], v[7]);
            }
    }
    __syncthreads();

    const int wc = tid % WW;
    const int hr = tid / WW;
    const bool active = tid < 4 * WW;
    float acc[2][8];
    #pragma unroll
    for (int d = 0; d < 2; ++d)
        #pragma unroll
        for (int t = 0; t < 8; ++t) acc[d][t] = 0.f;

    for (int cl = 0; cl < 8; ++cl) {
        const int c = chunk * 8 + cl;
        // issue next channel's global loads early (hidden under compute)
        float xn[2][8];
        if (cl < 7) {
            #pragma unroll
            for (int k = 0; k < 2; ++k)
                if (pvld[k]) {
                    #pragma unroll
                    for (int t = 0; t < 8; ++t)
                        xn[k][t] = x[((size_t)((b * 8 + t) * CC + c + 1)) * HW + pgoff[k]];
                }
        }
        // compute current channel from the single LDS buffer
        if (active) {
            const int ci = c & 127;
            const float* wp0 = gw0 + ((size_t)g * 128 + ci) * 27;
            const float* wp1 = gw1 + ((size_t)g * 128 + ci) * 27;
            #pragma unroll
            for (int ki = 0; ki < 3; ++ki) {
                #pragma unroll
                for (int kj = 0; kj < 3; ++kj) {
                    const int tap = ki * 3 + kj;
                    const int pos = (hr + ki) * 58 + wc + kj;
                    const float4 A = *(const float4*)(&tile[pos * 12]);
                    const float4 B = *(const float4*)(&tile[pos * 12 + 4]);
                    const float vv[8] = {A.x, A.y, A.z, A.w, B.x, B.y, B.z, B.w};
                    #pragma unroll
                    for (int kd = 0; kd < 3; ++kd) {
                        const float w0 = wp0[kd * 9 + tap];
                        const float w1 = wp1[kd * 9 + tap];
                        #pragma unroll
                        for (int t = 0; t < 8; ++t) {
                            const int to1 = t + 1 - kd;
                            if (to1 >= 0 && to1 < 8)
                                acc[0][to1] = fmaf(w0, vv[t], acc[0][to1]);
                            const int to2 = t + 2 - 2 * kd;
                            if (to2 >= 0 && to2 < 8)
                                acc[1][to2] = fmaf(w1, vv[t], acc[1][to2]);
                        }
                    }
                }
            }
        }
        __syncthreads();                    // all reads of ch c done
        if (cl < 7) {
            const float scn = scale[c + 1], shn = shift[c + 1];
            #pragma unroll
            for (int k = 0; k < 2; ++k)
                if (pvld[k]) {
                    float v[8];
                    #pragma unroll
                    for (int t = 0; t < 8; ++t)
                        v[t] = fmaxf(fmaf(xn[k][t] * pav[k][t], scn, shn), 0.f);
                    int p = tid + k * 256;
                    *(float4*)&tile[p * 12]     = make_float4(v[0], v[1], v[2], v[3]);
                    *(float4*)&tile[p * 12 + 4] = make_float4(v[4], v[5], v[6], v[7]);
                }
            __syncthreads();                // ch c+1 staged
        }
    }

    if (active) {
        const int hw = (h0 + hr) * WW + wc;
        #pragma unroll
        for (int d = 0; d < 2; ++d)
            #pragma unroll
            for (int t = 0; t < 8; ++t)
                atomicAdd(&gate_raw[(((size_t)(d * 4 + b) * 2 + g) * 8 + t) * HW + hw],
                          acc[d][t]);
    }
}

// ---------------- K4b: gate = tanh(raw + bias) ----------------------------
__global__ void k4b_tanh(const float* __restrict__ raw, const float* __restrict__ gb0,
                         const float* __restrict__ gb1, float* __restrict__ gt) {
    int i = blockIdx.x * 256 + threadIdx.x;
    if (i >= 401408) return;
    int d   = i / 200704;
    int rem = i - d * 200704;
    int g   = (rem / 25088) & 1;
    float bias = (d == 0) ? gb0[g] : gb1[g];
    gt[i] = tanhf(raw[i] + bias);
}

// ---------------- K5: fuse + shuffle + alpha-combine, float2-vectorized ---
// 8B/lane streaming (was 4B scalar): half the VMEM instructions for the
// same 206MB of traffic. Thread owns 2 hw positions across all 8 t.
// grid = b(4) x c(256) x tile(7 of 256 float2-positions) = 7168 blocks.
__global__ __launch_bounds__(256)
void k5_fuse(const float* __restrict__ x, const float* __restrict__ attn,
             const float* __restrict__ scale, const float* __restrict__ shift,
             const float* __restrict__ gt, const float* __restrict__ alpha,
             float* __restrict__ out) {
    const int blk  = blockIdx.x;
    const int tile = blk % 7;
    const int c    = (blk / 7) & 255;
    const int b    = blk / (7 * 256);
    const int p2   = tile * 256 + threadIdx.x;     // float2 index, 1568 total
    if (p2 >= HW / 2) return;
    const int hw   = p2 * 2;
    const int clo  = c & 127;
    const int cs   = (c & 128) | ((clo & 1) << 6) | (clo >> 1);  // inverse shuffle
    const int g    = c >> 7;
    const int head = cs >> 6;
    const float sc = scale[cs], sh = shift[cs];
    float2 xr[8], G0[8], G1[8];
    #pragma unroll
    for (int t = 0; t < 8; ++t) {
        const int bti = b * 8 + t;
        float2 xv = *(const float2*)&x[((size_t)bti * CC + cs) * HW + hw];
        float2 av = *(const float2*)&attn[((size_t)bti * 4 + head) * HW + hw];
        xr[t].x = fmaxf(fmaf(xv.x * av.x, sc, sh), 0.f);
        xr[t].y = fmaxf(fmaf(xv.y * av.y, sc, sh), 0.f);
        G0[t] = *(const float2*)&gt[(((size_t)(0 * 4 + b) * 2 + g) * 8 + t) * HW + hw];
        G1[t] = *(const float2*)&gt[(((size_t)(1 * 4 + b) * 2 + g) * 8 + t) * HW + hw];
    }
    const float a0 = alpha[0], a1 = alpha[1];
    #pragma unroll
    for (int t = 0; t < 8; ++t) {
        float2 v0, v1;
        if (g == 0) {   // shift-left group: neighbor at t+d
            v0.x = xr[t].x * (1.f - G0[t].x) + (t + 1 < 8 ? G0[t + 1].x * xr[t + 1].x : 0.f);
            v0.y = xr[t].y * (1.f - G0[t].y) + (t + 1 < 8 ? G0[t + 1].y * xr[t + 1].y : 0.f);
            v1.x = xr[t].x * (1.f - G1[t].x) + (t + 2 < 8 ? G1[t + 2].x * xr[t + 2].x : 0.f);
            v1.y = xr[t].y * (1.f - G1[t].y) + (t + 2 < 8 ? G1[t + 2].y * xr[t + 2].y : 0.f);
        } else {        // shift-right group: neighbor at t-d
            v0.x = xr[t].x * (1.f - G0[t].x) + (t - 1 >= 0 ? G0[t - 1].x * xr[t - 1].x : 0.f);
            v0.y = xr[t].y * (1.f - G0[t].y) + (t - 1 >= 0 ? G0[t - 1].y * xr[t - 1].y : 0.f);
            v1.x = xr[t].x * (1.f - G1[t].x) + (t - 2 >= 0 ? G1[t - 2].x * xr[t - 2].x : 0.f);
            v1.y = xr[t].y * (1.f - G1[t].y) + (t - 2 >= 0 ? G1[t - 2].y * xr[t - 2].y : 0.f);
        }
        float2 o;
        o.x = fmaf(a0, v0.x, a1 * v1.x);
        o.y = fmaf(a0, v0.y, a1 * v1.y);
        *(float2*)&out[((size_t)(b * 8 + t) * CC + c) * HW + hw] = o;
    }
}

extern "C" void kernel_launch(void* const* d_in, const int* in_sizes, int n_in,
                              void* d_out, int out_size, void* d_ws, size_t ws_size,
                              hipStream_t stream) {
    const float* x     = (const float*)d_in[0];
    const float* aw    = (const float*)d_in[1];
    const float* ab    = (const float*)d_in[2];
    const float* gamma = (const float*)d_in[3];
    const float* beta  = (const float*)d_in[4];
    const float* gw0   = (const float*)d_in[5];
    const float* gb0   = (const float*)d_in[6];
    const float* gw1   = (const float*)d_in[7];
    const float* gb1   = (const float*)d_in[8];
    const float* alpha = (const float*)d_in[9];
    float* out = (float*)d_out;
    float* ws  = (float*)d_ws;

    // ws layout (floats):
    //   [gate_raw 401408 | attn_raw/gate_t 401408 | bn_sum 256 | bn_sumsq 256 |
    //    attn 401408 | scale 256 | shift 256]
    float* gate_raw = ws;
    float* attn_raw = ws + 401408;
    float* gate_t   = attn_raw;             // alias (timeline-disjoint)
    float* bn_sum   = ws + 802816;
    float* bn_sumsq = ws + 803072;
    float* attn     = ws + 803328;
    float* scale    = ws + 1204736;
    float* shift    = ws + 1204992;

    // zero atomic-accumulated prefix: 803584 floats = 200896 float4s
    k0_zero <<<dim3(785),   dim3(256), 0, stream>>>((float4*)ws, 200896);

    k1_attn <<<dim3(3584),  dim3(256), 0, stream>>>(x, aw, attn_raw);
    k2_stats<<<dim3(8192),  dim3(256), 0, stream>>>(x, attn_raw, ab, attn, bn_sum, bn_sumsq);
    k3_final<<<dim3(1),     dim3(256), 0, stream>>>(bn_sum, bn_sumsq, gamma, beta, scale, shift);
    k4_gate <<<dim3(1792),  dim3(256), 0, stream>>>(x, attn, scale, shift, gw0, gw1, gate_raw);
    k4b_tanh<<<dim3(1568),  dim3(256), 0, stream>>>(gate_raw, gb0, gb1, gate_t);
    k5_fuse <<<dim3(7168),  dim3(256), 0, stream>>>(x, attn, scale, shift, gate_t, alpha, out);
}

// Round 20
// 159.178 us; speedup vs baseline: 1.0425x; 1.0425x over previous
//
#include <hip/hip_runtime.h>
#include <math.h>

#define HH 56
#define WW 56
#define CC 256
#define TT 8
#define HW 3136

// ---------------- K0: zero workspace (replaces slow runtime fill) ---------
__global__ void k0_zero(float4* __restrict__ p, int n4) {
    int i = blockIdx.x * 256 + threadIdx.x;
    if (i < n4) p[i] = make_float4(0.f, 0.f, 0.f, 0.f);
}

// ---------------- K1: attn conv2d, channel-vectorized LDS (r11 exact) -----
// 4-ch windows (144 weights = SGPR-budget sweet spot; 8-ch demotes weights
// to VALU loads, 3x regression - r13/r14). csplit 8 -> 3584 blocks.
__global__ __launch_bounds__(256)
void k1_attn(const float* __restrict__ x, const float* __restrict__ aw,
             float* __restrict__ attn_raw) {
    const int blk = blockIdx.x;
    const int cs  = blk & 7;
    const int ht  = (blk >> 3) % 14;
    const int bt  = blk / 112;
    const int h0  = ht * 4;
    __shared__ float tile[2][348 * 4];      // 11136 B
    const int tid = threadIdx.x;
    const float* xb = x + ((size_t)bt * CC + cs * 32) * HW;

    int  pgoff[2];
    bool pvld[2];
    #pragma unroll
    for (int k = 0; k < 2; ++k) {
        int p = tid + k * 256;
        bool in = p < 348;
        int r   = p / 58;
        int col = p - r * 58;
        int gh = h0 + r - 1, gw = col - 1;
        bool v = in && (unsigned)gh < HH && (unsigned)gw < WW;
        pvld[k]  = v;
        pgoff[k] = gh * WW + gw;
        if (in && !v) {
            float4 z = make_float4(0.f, 0.f, 0.f, 0.f);
            *(float4*)&tile[0][p * 4] = z;
            *(float4*)&tile[1][p * 4] = z;
        }
    }

    #pragma unroll
    for (int k = 0; k < 2; ++k)
        if (pvld[k]) {
            float v0 = xb[(size_t)0 * HW + pgoff[k]];
            float v1 = xb[(size_t)1 * HW + pgoff[k]];
            float v2 = xb[(size_t)2 * HW + pgoff[k]];
            float v3 = xb[(size_t)3 * HW + pgoff[k]];
            *(float4*)&tile[0][(tid + k * 256) * 4] = make_float4(v0, v1, v2, v3);
        }
    __syncthreads();

    const int wc = tid % WW;
    const int hr = tid / WW;
    const bool active = tid < 4 * WW;
    float acc[4] = {0.f, 0.f, 0.f, 0.f};

    for (int it = 0; it < 8; ++it) {
        const int c0 = cs * 32 + it * 4;
        float xn[2][4];
        if (it < 7) {
            #pragma unroll
            for (int k = 0; k < 2; ++k)
                if (pvld[k]) {
                    #pragma unroll
                    for (int j = 0; j < 4; ++j)
                        xn[k][j] = xb[(size_t)(it * 4 + 4 + j) * HW + pgoff[k]];
                }
        }
        if (active) {
            const float* buf = &tile[it & 1][0];
            const float* w0 = aw + ((size_t)0 * CC + c0) * 9;
            const float* w1 = aw + ((size_t)1 * CC + c0) * 9;
            const float* w2 = aw + ((size_t)2 * CC + c0) * 9;
            const float* w3 = aw + ((size_t)3 * CC + c0) * 9;
            #pragma unroll
            for (int ki = 0; ki < 3; ++ki) {
                #pragma unroll
                for (int kj = 0; kj < 3; ++kj) {
                    const int tap = ki * 3 + kj;
                    const int pos = (hr + ki) * 58 + wc + kj;
                    const float4 v = *(const float4*)(buf + pos * 4);
                    acc[0] = fmaf(w0[tap],      v.x, acc[0]);
                    acc[0] = fmaf(w0[9  + tap], v.y, acc[0]);
                    acc[0] = fmaf(w0[18 + tap], v.z, acc[0]);
                    acc[0] = fmaf(w0[27 + tap], v.w, acc[0]);
                    acc[1] = fmaf(w1[tap],      v.x, acc[1]);
                    acc[1] = fmaf(w1[9  + tap], v.y, acc[1]);
                    acc[1] = fmaf(w1[18 + tap], v.z, acc[1]);
                    acc[1] = fmaf(w1[27 + tap], v.w, acc[1]);
                    acc[2] = fmaf(w2[tap],      v.x, acc[2]);
                    acc[2] = fmaf(w2[9  + tap], v.y, acc[2]);
                    acc[2] = fmaf(w2[18 + tap], v.z, acc[2]);
                    acc[2] = fmaf(w2[27 + tap], v.w, acc[2]);
                    acc[3] = fmaf(w3[tap],      v.x, acc[3]);
                    acc[3] = fmaf(w3[9  + tap], v.y, acc[3]);
                    acc[3] = fmaf(w3[18 + tap], v.z, acc[3]);
                    acc[3] = fmaf(w3[27 + tap], v.w, acc[3]);
                }
            }
        }
        if (it < 7) {
            float* bufn = &tile[(it + 1) & 1][0];
            #pragma unroll
            for (int k = 0; k < 2; ++k)
                if (pvld[k])
                    *(float4*)&bufn[(tid + k * 256) * 4] =
                        make_float4(xn[k][0], xn[k][1], xn[k][2], xn[k][3]);
        }
        __syncthreads();
    }

    if (active) {
        const int base = (h0 + hr) * WW + wc;
        #pragma unroll
        for (int h = 0; h < 4; ++h)
            atomicAdd(&attn_raw[((size_t)bt * 4 + h) * HW + base], acc[h]);
    }
}

// ---------------- K2: BN stats, attn-plane-in-registers -------------------
// block = (bt, head, csub16): activate the head's attn plane ONCE into 4
// float4 regs/thread (old layout recomputed the sigmoid 64x per plane and
// re-read attn_raw 102MB), then loop 4 channels of x against it.
// csub==0 blocks materialize attn (128 writers, same as before).
__global__ __launch_bounds__(256)
void k2_stats(const float* __restrict__ x, const float* __restrict__ attn_raw,
              const float* __restrict__ ab, float* __restrict__ attn,
              float* __restrict__ bn_sum, float* __restrict__ bn_sumsq) {
    const int blk  = blockIdx.x;            // 2048 = bt(32) x head(4) x csub(16)
    const int csub = blk & 15;
    const int head = (blk >> 4) & 3;
    const int bt   = blk >> 6;
    const float bias = ab[head];
    const int tid = threadIdx.x;
    const float4* rp = (const float4*)(attn_raw + ((size_t)bt * 4 + head) * HW);
    float4* ap = (float4*)(attn + ((size_t)bt * 4 + head) * HW);

    float4 av[4];
    #pragma unroll
    for (int k = 0; k < 4; ++k) {
        int i = tid + k * 256;
        if (i < HW / 4) {
            float4 rv = rp[i];
            av[k].x = 1.f / (1.f + expf(-fmaxf(rv.x + bias, 0.f)));
            av[k].y = 1.f / (1.f + expf(-fmaxf(rv.y + bias, 0.f)));
            av[k].z = 1.f / (1.f + expf(-fmaxf(rv.z + bias, 0.f)));
            av[k].w = 1.f / (1.f + expf(-fmaxf(rv.w + bias, 0.f)));
            if (csub == 0) ap[i] = av[k];
        }
    }

    __shared__ float red[4][8];
    const int wave = tid >> 6;
    const int c0 = head * 64 + csub * 4;
    #pragma unroll
    for (int cl = 0; cl < 4; ++cl) {
        const float4* xp = (const float4*)(x + ((size_t)bt * CC + c0 + cl) * HW);
        float s = 0.f, s2 = 0.f;
        #pragma unroll
        for (int k = 0; k < 4; ++k) {
            int i = tid + k * 256;
            if (i < HW / 4) {
                float4 xv = xp[i];
                float v0 = xv.x * av[k].x, v1 = xv.y * av[k].y;
                float v2 = xv.z * av[k].z, v3 = xv.w * av[k].w;
                s  += v0 + v1 + v2 + v3;
                s2 += v0 * v0 + v1 * v1 + v2 * v2 + v3 * v3;
            }
        }
        #pragma unroll
        for (int off = 32; off > 0; off >>= 1) {
            s  += __shfl_down(s, off);
            s2 += __shfl_down(s2, off);
        }
        if ((tid & 63) == 0) { red[cl][wave * 2] = s; red[cl][wave * 2 + 1] = s2; }
    }
    __syncthreads();
    if (tid < 4) {
        atomicAdd(&bn_sum[c0 + tid],
                  red[tid][0] + red[tid][2] + red[tid][4] + red[tid][6]);
        atomicAdd(&bn_sumsq[c0 + tid],
                  red[tid][1] + red[tid][3] + red[tid][5] + red[tid][7]);
    }
}

// ---------------- K3: finalize BN -> per-channel scale/shift --------------
__global__ void k3_final(const float* __restrict__ bn_sum, const float* __restrict__ bn_sumsq,
                         const float* __restrict__ gamma, const float* __restrict__ beta,
                         float* __restrict__ scale, float* __restrict__ shift) {
    int c = threadIdx.x;
    const float invN = 1.f / 100352.f;            // B*T*H*W
    float mean = bn_sum[c] * invN;
    float var  = bn_sumsq[c] * invN - mean * mean;
    float sc   = gamma[c] * rsqrtf(var + 1e-5f);
    scale[c] = sc;
    shift[c] = fmaf(-mean, sc, beta[c]);
}

// ---------------- K4: grouped dilated conv3d, t-vectorized single-buffer --
// r16 exact (best measured). NO launch_bounds min-waves: forcing 7 waves/EU
// (r17) made the compiler spill acc[] to scratch. 80 VGPR / 6 blocks/CU.
__global__ __launch_bounds__(256)
void k4_gate(const float* __restrict__ x, const float* __restrict__ attn,
             const float* __restrict__ scale, const float* __restrict__ shift,
             const float* __restrict__ gw0, const float* __restrict__ gw1,
             float* __restrict__ gate_raw) {
    const int blk   = blockIdx.x;
    const int chunk = blk & 31;             // 32 chunks x 8 channels
    const int ht    = (blk >> 5) % 14;
    const int b     = blk / (32 * 14);
    const int h0    = ht * 4;
    const int g     = chunk >> 4;           // group: ch 0..127 -> 0, else 1
    const int head  = chunk >> 3;           // 8-ch chunk sits inside one head
    __shared__ float tile[348 * 12];        // 16704 B (single buffer)
    const int tid = threadIdx.x;

    int   pgoff[2];
    bool  pvld[2];
    float pav[2][8];
    #pragma unroll
    for (int k = 0; k < 2; ++k) {
        int p = tid + k * 256;
        bool in = p < 348;
        int r   = p / 58;
        int col = p - r * 58;
        int gh = h0 + r - 1, gw = col - 1;
        bool v = in && (unsigned)gh < HH && (unsigned)gw < WW;
        pvld[k]  = v;
        pgoff[k] = gh * WW + gw;
        #pragma unroll
        for (int t = 0; t < 8; ++t)
            pav[k][t] = v ? attn[((size_t)(b * 8 + t) * 4 + head) * HW + pgoff[k]] : 0.f;
        if (in && !v) {                      // zero halo once
            float4 z = make_float4(0.f, 0.f, 0.f, 0.f);
            *(float4*)&tile[p * 12]     = z;
            *(float4*)&tile[p * 12 + 4] = z;
        }
    }

    // stage channel 0
    {
        const int c0 = chunk * 8;
        const float sc = scale[c0], sh = shift[c0];
        #pragma unroll
        for (int k = 0; k < 2; ++k)
            if (pvld[k]) {
                float v[8];
                #pragma unroll
                for (int t = 0; t < 8; ++t) {
                    float xv = x[((size_t)((b * 8 + t) * CC + c0)) * HW + pgoff[k]];
                    v[t] = fmaxf(fmaf(xv * pav[k][t], sc, sh), 0.f);
                }
                int p = tid + k * 256;
                *(float4*)&tile[p * 12]     = make_float4(v[0], v[1], v[2], v[3]);
                *(float4*)&tile[p * 12 + 4] = make_float4(v[4], v[5], v[6], v[7]);
            }
    }
    __syncthreads();

    const int wc = tid % WW;
    const int hr = tid / WW;
    const bool active = tid < 4 * WW;
    float acc[2][8];
    #pragma unroll
    for (int d = 0; d < 2; ++d)
        #pragma unroll
        for (int t = 0; t < 8; ++t) acc[d][t] = 0.f;

    for (int cl = 0; cl < 8; ++cl) {
        const int c = chunk * 8 + cl;
        // issue next channel's global loads early (hidden under compute)
        float xn[2][8];
        if (cl < 7) {
            #pragma unroll
            for (int k = 0; k < 2; ++k)
                if (pvld[k]) {
                    #pragma unroll
                    for (int t = 0; t < 8; ++t)
                        xn[k][t] = x[((size_t)((b * 8 + t) * CC + c + 1)) * HW + pgoff[k]];
                }
        }
        // compute current channel from the single LDS buffer
        if (active) {
            const int ci = c & 127;
            const float* wp0 = gw0 + ((size_t)g * 128 + ci) * 27;
            const float* wp1 = gw1 + ((size_t)g * 128 + ci) * 27;
            #pragma unroll
            for (int ki = 0; ki < 3; ++ki) {
                #pragma unroll
                for (int kj = 0; kj < 3; ++kj) {
                    const int tap = ki * 3 + kj;
                    const int pos = (hr + ki) * 58 + wc + kj;
                    const float4 A = *(const float4*)(&tile[pos * 12]);
                    const float4 B = *(const float4*)(&tile[pos * 12 + 4]);
                    const float vv[8] = {A.x, A.y, A.z, A.w, B.x, B.y, B.z, B.w};
                    #pragma unroll
                    for (int kd = 0; kd < 3; ++kd) {
                        const float w0 = wp0[kd * 9 + tap];
                        const float w1 = wp1[kd * 9 + tap];
                        #pragma unroll
                        for (int t = 0; t < 8; ++t) {
                            const int to1 = t + 1 - kd;
                            if (to1 >= 0 && to1 < 8)
                                acc[0][to1] = fmaf(w0, vv[t], acc[0][to1]);
                            const int to2 = t + 2 - 2 * kd;
                            if (to2 >= 0 && to2 < 8)
                                acc[1][to2] = fmaf(w1, vv[t], acc[1][to2]);
                        }
                    }
                }
            }
        }
        __syncthreads();                    // all reads of ch c done
        if (cl < 7) {
            const float scn = scale[c + 1], shn = shift[c + 1];
            #pragma unroll
            for (int k = 0; k < 2; ++k)
                if (pvld[k]) {
                    float v[8];
                    #pragma unroll
                    for (int t = 0; t < 8; ++t)
                        v[t] = fmaxf(fmaf(xn[k][t] * pav[k][t], scn, shn), 0.f);
                    int p = tid + k * 256;
                    *(float4*)&tile[p * 12]     = make_float4(v[0], v[1], v[2], v[3]);
                    *(float4*)&tile[p * 12 + 4] = make_float4(v[4], v[5], v[6], v[7]);
                }
            __syncthreads();                // ch c+1 staged
        }
    }

    if (active) {
        const int hw = (h0 + hr) * WW + wc;
        #pragma unroll
        for (int d = 0; d < 2; ++d)
            #pragma unroll
            for (int t = 0; t < 8; ++t)
                atomicAdd(&gate_raw[(((size_t)(d * 4 + b) * 2 + g) * 8 + t) * HW + hw],
                          acc[d][t]);
    }
}

// ---------------- K4b: gate = tanh(raw + bias) ----------------------------
__global__ void k4b_tanh(const float* __restrict__ raw, const float* __restrict__ gb0,
                         const float* __restrict__ gb1, float* __restrict__ gt) {
    int i = blockIdx.x * 256 + threadIdx.x;
    if (i >= 401408) return;
    int d   = i / 200704;
    int rem = i - d * 200704;
    int g   = (rem / 25088) & 1;
    float bias = (d == 0) ? gb0[g] : gb1[g];
    gt[i] = tanhf(raw[i] + bias);
}

// ---------------- K5: fuse + shuffle + alpha-combine (r18 exact) ----------
__global__ __launch_bounds__(256)
void k5_fuse(const float* __restrict__ x, const float* __restrict__ attn,
             const float* __restrict__ scale, const float* __restrict__ shift,
             const float* __restrict__ gt, const float* __restrict__ alpha,
             float* __restrict__ out) {
    const int blk  = blockIdx.x;
    const int tile = blk % 13;
    const int c    = (blk / 13) & 255;
    const int b    = blk / (13 * 256);
    const int hw   = tile * 256 + threadIdx.x;
    if (hw >= HW) return;
    const int clo  = c & 127;
    const int cs   = (c & 128) | ((clo & 1) << 6) | (clo >> 1);  // inverse shuffle
    const int g    = c >> 7;
    const int head = cs >> 6;
    const float sc = scale[cs], sh = shift[cs];
    float xr[8], G0[8], G1[8];
    #pragma unroll
    for (int t = 0; t < 8; ++t) {
        const int bti = b * 8 + t;
        float xv = x[((size_t)bti * CC + cs) * HW + hw];
        float av = attn[((size_t)bti * 4 + head) * HW + hw];
        xr[t] = fmaxf(fmaf(xv * av, sc, sh), 0.f);
        G0[t] = gt[(((size_t)(0 * 4 + b) * 2 + g) * 8 + t) * HW + hw];
        G1[t] = gt[(((size_t)(1 * 4 + b) * 2 + g) * 8 + t) * HW + hw];
    }
    const float a0 = alpha[0], a1 = alpha[1];
    #pragma unroll
    for (int t = 0; t < 8; ++t) {
        float v0, v1;
        if (g == 0) {
            v0 = xr[t] * (1.f - G0[t]) + (t + 1 < 8 ? G0[t + 1] * xr[t + 1] : 0.f);
            v1 = xr[t] * (1.f - G1[t]) + (t + 2 < 8 ? G1[t + 2] * xr[t + 2] : 0.f);
        } else {
            v0 = xr[t] * (1.f - G0[t]) + (t - 1 >= 0 ? G0[t - 1] * xr[t - 1] : 0.f);
            v1 = xr[t] * (1.f - G1[t]) + (t - 2 >= 0 ? G1[t - 2] * xr[t - 2] : 0.f);
        }
        out[((size_t)(b * 8 + t) * CC + c) * HW + hw] = fmaf(a0, v0, a1 * v1);
    }
}

extern "C" void kernel_launch(void* const* d_in, const int* in_sizes, int n_in,
                              void* d_out, int out_size, void* d_ws, size_t ws_size,
                              hipStream_t stream) {
    const float* x     = (const float*)d_in[0];
    const float* aw    = (const float*)d_in[1];
    const float* ab    = (const float*)d_in[2];
    const float* gamma = (const float*)d_in[3];
    const float* beta  = (const float*)d_in[4];
    const float* gw0   = (const float*)d_in[5];
    const float* gb0   = (const float*)d_in[6];
    const float* gw1   = (const float*)d_in[7];
    const float* gb1   = (const float*)d_in[8];
    const float* alpha = (const float*)d_in[9];
    float* out = (float*)d_out;
    float* ws  = (float*)d_ws;

    // ws layout (floats):
    //   [gate_raw 401408 | attn_raw/gate_t 401408 | bn_sum 256 | bn_sumsq 256 |
    //    attn 401408 | scale 256 | shift 256]
    float* gate_raw = ws;
    float* attn_raw = ws + 401408;
    float* gate_t   = attn_raw;             // alias (timeline-disjoint)
    float* bn_sum   = ws + 802816;
    float* bn_sumsq = ws + 803072;
    float* attn     = ws + 803328;
    float* scale    = ws + 1204736;
    float* shift    = ws + 1204992;

    // zero atomic-accumulated prefix: 803584 floats = 200896 float4s
    k0_zero <<<dim3(785),   dim3(256), 0, stream>>>((float4*)ws, 200896);

    k1_attn <<<dim3(3584),  dim3(256), 0, stream>>>(x, aw, attn_raw);
    k2_stats<<<dim3(2048),  dim3(256), 0, stream>>>(x, attn_raw, ab, attn, bn_sum, bn_sumsq);
    k3_final<<<dim3(1),     dim3(256), 0, stream>>>(bn_sum, bn_sumsq, gamma, beta, scale, shift);
    k4_gate <<<dim3(1792),  dim3(256), 0, stream>>>(x, attn, scale, shift, gw0, gw1, gate_raw);
    k4b_tanh<<<dim3(1568),  dim3(256), 0, stream>>>(gate_raw, gb0, gb1, gate_t);
    k5_fuse <<<dim3(13312), dim3(256), 0, stream>>>(x, attn, scale, shift, gate_t, alpha, out);
}